// Round 3
// baseline (219.525 us; speedup 1.0000x reference)
//
#include <hip/hip_runtime.h>
#include <math.h>

#define NB    128
#define NC    16      // LDS histogram replicas
#define CSTR  129     // LDS replica stride (spreads banks)
#define GC    16      // global histogram replicas (cuts atomic contention 16x)

// ndtr via Abramowitz-Stegun 7.1.26 erf approximation. Branchless.
// |abs err| <= 1.5e-7 over full range -> ~2.4e-6 on normalized output.
__device__ __forceinline__ float fast_ndtr(float z) {
    const float is2 = 0.70710678118654752440f;
    float x = z * is2;
    float a = fabsf(x);
    float t = __builtin_amdgcn_rcpf(fmaf(0.3275911f, a, 1.0f));
    float p = t * fmaf(t, fmaf(t, fmaf(t, fmaf(t, 1.061405429f, -1.453152027f),
                                       1.421413741f), -0.284496736f), 0.254829592f);
    float e = __expf(-a * a);
    float erfa = fmaf(-p, e, 1.0f);           // erf(|x|)
    float se = (x >= 0.0f) ? erfa : -erfa;    // erf is odd
    return fmaf(0.5f, se, 0.5f);
}

__global__ __launch_bounds__(256) void hist_kernel(const float* __restrict__ x,
                                                   const float* __restrict__ edges,
                                                   float* __restrict__ ws,
                                                   float* __restrict__ out, int n) {
    __shared__ float sh[NC * CSTR];
    __shared__ int is_last;
    for (int i = threadIdx.x; i < NC * CSTR; i += 256) sh[i] = 0.0f;
    __syncthreads();

    const float e0 = edges[0];
    const float res = edges[1] - e0;           // 0.0625 exactly
    const float inv_res = 1.0f / res;
    const int cbase = (threadIdx.x & (NC - 1)) * CSTR;
    const int stride = gridDim.x * 256;

    for (int i = blockIdx.x * 256 + threadIdx.x; i < n; i += stride) {
        float t = (x[i * 6] - e0) * inv_res;   // AXIS=0; z_j = j - t (edges 1 bw apart)
        int j0 = (int)ceilf(t - 5.5f);         // tail cut: ndtr(-4.5) = 3.4e-6
        int j1 = (int)floorf(t + 4.5f);
        j0 = max(j0, 0);
        j1 = min(j1, NB - 1);
        if (j0 > j1) continue;
        float cp = fast_ndtr((float)j0 - t);
        for (int j = j0; j <= j1; ++j) {
            float cn = fast_ndtr((float)(j + 1) - t);
            unsafeAtomicAdd(&sh[cbase + j], cn - cp);   // native ds_add_f32
            cp = cn;
        }
    }
    __syncthreads();

    // fold the 16 LDS replicas, add into this block's global replica
    float* gbin = ws;                                     // GC*NB floats
    unsigned* cnt = (unsigned*)(ws + GC * NB);            // ticket counter
    const int grep = (blockIdx.x & (GC - 1)) * NB;
    if (threadIdx.x < NB) {
        float v = 0.0f;
        #pragma unroll
        for (int c = 0; c < NC; ++c) v += sh[c * CSTR + threadIdx.x];
        unsafeAtomicAdd(&gbin[grep + threadIdx.x], v);    // native global_atomic_add_f32
    }
    __threadfence();                                      // release our adds
    __syncthreads();
    if (threadIdx.x == 0) {
        unsigned old = atomicAdd(cnt, 1u);                // device-scope
        is_last = (old == gridDim.x - 1) ? 1 : 0;
    }
    __syncthreads();

    if (is_last) {                                        // exactly one block
        __threadfence();                                  // acquire side
        float v = 0.0f;
        if (threadIdx.x < NB) {
            #pragma unroll
            for (int c = 0; c < GC; ++c)
                v += __hip_atomic_load(&gbin[c * NB + threadIdx.x],
                                       __ATOMIC_RELAXED, __HIP_MEMORY_SCOPE_AGENT);
            sh[threadIdx.x] = v;
        }
        __syncthreads();
        for (int off = 64; off >= 1; off >>= 1) {         // total = sum of bins
            if (threadIdx.x < off) sh[threadIdx.x] += sh[threadIdx.x + off];
            __syncthreads();
        }
        if (threadIdx.x < NB) out[threadIdx.x] = v / (sh[0] * res);
    }
}

extern "C" void kernel_launch(void* const* d_in, const int* in_sizes, int n_in,
                              void* d_out, int out_size, void* d_ws, size_t ws_size,
                              hipStream_t stream) {
    const float* x     = (const float*)d_in[0];
    const float* edges = (const float*)d_in[1];
    float* out = (float*)d_out;
    float* ws  = (float*)d_ws;
    int n = in_sizes[0] / 6;

    // zero the GC*NB global bins + ticket counter (ws is poisoned 0xAA each call)
    hipMemsetAsync(ws, 0, (GC * NB + 1) * sizeof(float), stream);
    hist_kernel<<<2048, 256, 0, stream>>>(x, edges, ws, out, n);
}

// Round 4
// 190.852 us; speedup vs baseline: 1.1502x; 1.1502x over previous
//
#include <hip/hip_runtime.h>
#include <math.h>

#define NB    128
#define NC    16          // LDS histogram replicas
#define CSTR  129         // LDS replica stride in u32 (129 % 32 == 1 -> spreads banks)
#define GC    8           // global u64 histogram replicas
#define QSCALE 2097152.0f // 2^21 fixed-point scale

// ndtr via A&S 7.1.26 erf approx. |err| <= 1.5e-7. Branchless.
__device__ __forceinline__ float fast_ndtr(float z) {
    const float is2 = 0.70710678118654752440f;
    float x = z * is2;
    float a = fabsf(x);
    float t = __builtin_amdgcn_rcpf(fmaf(0.3275911f, a, 1.0f));
    float p = t * fmaf(t, fmaf(t, fmaf(t, fmaf(t, 1.061405429f, -1.453152027f),
                                       1.421413741f), -0.284496736f), 0.254829592f);
    float e = __expf(-a * a);
    float erfa = fmaf(-p, e, 1.0f);
    float se = (x >= 0.0f) ? erfa : -erfa;
    return fmaf(0.5f, se, 0.5f);
}

__device__ __forceinline__ void accum_point(float xv, float e0, float inv_res,
                                            unsigned* sh, int cbase) {
    float t = (xv - e0) * inv_res;          // z_j = j - t (edges exactly 1 bw apart)
    int j0 = (int)ceilf(t - 5.5f);          // window: ndtr beyond +-4.5 ~ {0,1}
    int j1 = (int)floorf(t + 4.5f);
    j0 = max(j0, 0);
    j1 = min(j1, NB - 1);
    if (j0 > j1) return;
    float cp = fast_ndtr((float)j0 - t);
    for (int j = j0; j <= j1; ++j) {
        float cn = fast_ndtr((float)(j + 1) - t);
        float d = cn - cp;
        unsigned q = (unsigned)fmaxf(fmaf(d, QSCALE, 0.5f), 0.0f);  // round-to-nearest
        atomicAdd(&sh[cbase + j], q);       // native ds_add_u32 (integer: no CAS path)
        cp = cn;
    }
}

__global__ __launch_bounds__(256) void hist_kernel(const float* __restrict__ x,
                                                   const float* __restrict__ edges,
                                                   unsigned long long* __restrict__ gbin,
                                                   float* __restrict__ out, int n) {
    __shared__ unsigned sh[NC * CSTR];
    __shared__ unsigned long long red[NB];
    __shared__ int is_last;
    for (int i = threadIdx.x; i < NC * CSTR; i += 256) sh[i] = 0u;
    __syncthreads();

    const float e0 = edges[0];
    const float res = edges[1] - e0;
    const float inv_res = 1.0f / res;
    const int cbase = (threadIdx.x & (NC - 1)) * CSTR;
    const int stride = gridDim.x * 256;

    // software-pipelined grid-stride loop (~2 points/thread)
    int i = blockIdx.x * 256 + threadIdx.x;
    bool valid = i < n;
    float xv = valid ? x[(size_t)i * 6] : 0.0f;   // AXIS=0 of row-major (N,6)
    while (valid) {
        int inext = i + stride;
        bool vn = inext < n;
        float xn = vn ? x[(size_t)inext * 6] : 0.0f;
        accum_point(xv, e0, inv_res, sh, cbase);
        i = inext; xv = xn; valid = vn;
    }
    __syncthreads();

    // fold 16 LDS replicas -> one native u64 global atomic per bin
    unsigned* cnt = (unsigned*)(gbin + GC * NB);
    const int grep = (blockIdx.x & (GC - 1)) * NB;
    if (threadIdx.x < NB) {
        unsigned v = 0u;
        #pragma unroll
        for (int c = 0; c < NC; ++c) v += sh[c * CSTR + threadIdx.x];
        if (v) atomicAdd(&gbin[grep + threadIdx.x], (unsigned long long)v);
    }
    __threadfence();
    __syncthreads();
    if (threadIdx.x == 0) {
        unsigned old = atomicAdd(cnt, 1u);            // device-scope ticket
        is_last = (old == gridDim.x - 1) ? 1 : 0;
    }
    __syncthreads();

    if (is_last) {                                    // exactly one block: 2 KB reduce
        __threadfence();
        unsigned long long v = 0ull;
        if (threadIdx.x < NB) {
            #pragma unroll
            for (int c = 0; c < GC; ++c)
                v += __hip_atomic_load(&gbin[c * NB + threadIdx.x],
                                       __ATOMIC_RELAXED, __HIP_MEMORY_SCOPE_AGENT);
            red[threadIdx.x] = v;
        }
        __syncthreads();
        for (int off = 64; off >= 1; off >>= 1) {
            if (threadIdx.x < off) red[threadIdx.x] += red[threadIdx.x + off];
            __syncthreads();
        }
        if (threadIdx.x < NB) {
            double total = (double)red[0];
            out[threadIdx.x] = (float)((double)v / (total * (double)res));
        }
    }
}

extern "C" void kernel_launch(void* const* d_in, const int* in_sizes, int n_in,
                              void* d_out, int out_size, void* d_ws, size_t ws_size,
                              hipStream_t stream) {
    const float* x     = (const float*)d_in[0];
    const float* edges = (const float*)d_in[1];
    float* out = (float*)d_out;
    unsigned long long* gbin = (unsigned long long*)d_ws;
    int n = in_sizes[0] / 6;

    // zero GC*NB u64 bins + ticket (ws is poisoned 0xAA before every call)
    hipMemsetAsync(d_ws, 0, GC * NB * sizeof(unsigned long long) + sizeof(unsigned), stream);
    hist_kernel<<<2048, 256, 0, stream>>>(x, edges, gbin, out, n);
}